// Round 2
// baseline (556.073 us; speedup 1.0000x reference)
//
#include <hip/hip_runtime.h>
#include <math.h>

typedef unsigned short u16;
typedef unsigned int   u32;
typedef __attribute__((ext_vector_type(8))) short short8;
typedef __attribute__((ext_vector_type(4))) float floatx4;

#define MFMA16(a,b,c) __builtin_amdgcn_mfma_f32_16x16x32_bf16((a),(b),(c),0,0,0)

constexpr int BB  = 2;
constexpr int NT  = 2240;
constexpr int CD  = 384;
constexpr int NH  = 6;
constexpr int HD  = 64;
constexpr int HID = 1536;
constexpr int M   = BB * NT;       // 4480
constexpr int CS  = 5;             // attn column chunks
constexpr int CTILES = NT / 64 / CS;  // 7 col-tiles per chunk
constexpr float SCALE = 0.125f;

__device__ inline u16 f2bf(float f) {
  u32 u = __float_as_uint(f);
  u = (u + 0x7fffu + ((u >> 16) & 1u)) >> 16;
  return (u16)u;
}

// ---------------- weight fp32 -> bf16 convert ----------------
__global__ void cvt_bf16(const float* __restrict__ src, u16* __restrict__ dst, int n) {
  int i = (blockIdx.x * 256 + threadIdx.x) * 4;
  if (i < n) {
    float4 v = *(const float4*)(src + i);
    ushort4 o; o.x = f2bf(v.x); o.y = f2bf(v.y); o.z = f2bf(v.z); o.w = f2bf(v.w);
    *(ushort4*)(dst + i) = o;
  }
}

// ---------------- out = resid + bias (row-broadcast) ----------------
__global__ void init_add(const float* __restrict__ resid, const float* __restrict__ bias,
                         float* __restrict__ outf) {
  int i = (blockIdx.x * 256 + threadIdx.x) * 4;
  float4 r = *(const float4*)(resid + i);
  float4 b = *(const float4*)(bias + (i % CD));
  r.x += b.x; r.y += b.y; r.z += b.z; r.w += b.w;
  *(float4*)(outf + i) = r;
}

// ---------------- layernorm (+optional pos add, +optional x save) ----------------
__global__ __launch_bounds__(128) void ln_kernel(
    const float* __restrict__ xin, const float* __restrict__ pos,
    const float* __restrict__ g, const float* __restrict__ bta,
    float* __restrict__ x1out, u16* __restrict__ hout) {
  int row = blockIdx.x;
  int n = row % NT;
  int t = threadIdx.x;
  const float* xr = xin + (size_t)row * CD;
  float v[3], s1 = 0.f, s2 = 0.f;
  #pragma unroll
  for (int j = 0; j < 3; ++j) {
    int c = t + j * 128;
    float x = xr[c];
    if (pos) x += pos[(size_t)n * CD + c];
    v[j] = x; s1 += x; s2 += x * x;
  }
  #pragma unroll
  for (int off = 32; off; off >>= 1) { s1 += __shfl_down(s1, off); s2 += __shfl_down(s2, off); }
  __shared__ float rbuf[4];
  __shared__ float stats[2];
  int lane = t & 63, wid = t >> 6;
  if (lane == 0) { rbuf[wid] = s1; rbuf[2 + wid] = s2; }
  __syncthreads();
  if (t == 0) {
    float a = rbuf[0] + rbuf[1], b2 = rbuf[2] + rbuf[3];
    float mu = a / CD;
    float var = b2 / CD - mu * mu;
    stats[0] = mu; stats[1] = rsqrtf(var + 1e-5f);
  }
  __syncthreads();
  float mu = stats[0], rs = stats[1];
  #pragma unroll
  for (int j = 0; j < 3; ++j) {
    int c = t + j * 128;
    float h = (v[j] - mu) * rs * g[c] + bta[c];
    hout[(size_t)row * CD + c] = f2bf(h);
    if (x1out) x1out[(size_t)row * CD + c] = v[j];
  }
}

// ---------------- bf16 GEMM: out[M,N] = A[M,K] @ W[N,K]^T ----------------
// EPI: 0=qkv scatter, 1=proj(atomic add f32), 2=fc1(bias+gelu->bf16), 3=fc2(atomic add f32)
template <int EPI, int SPLITK>
__global__ __launch_bounds__(256) void gemm_bt(
    const u16* __restrict__ A, const u16* __restrict__ Wt, int K,
    const float* __restrict__ bias,
    float* __restrict__ outf, u16* __restrict__ outb,
    u16* __restrict__ qout, u16* __restrict__ kout, u16* __restrict__ vtout) {
  __shared__ __align__(16) u16 As[64][72];
  __shared__ __align__(16) u16 Bs[64][72];
  int m0 = blockIdx.y * 64, n0 = blockIdx.x * 64;
  int Ksub = K / SPLITK;
  int koff = blockIdx.z * Ksub;
  int t = threadIdx.x;
  int lane = t & 63, w = t >> 6, wm = w & 1, wn = w >> 1;
  int quad = lane >> 4, c16 = lane & 15;
  int lrow = t >> 2, lseg = t & 3;
  const u16* ga = A + (size_t)(m0 + lrow) * K + koff + lseg * 8;
  const u16* gb = Wt + (size_t)(n0 + lrow) * K + koff + lseg * 8;
  floatx4 acc[2][2] = {};
  for (int k0 = 0; k0 < Ksub; k0 += 64) {
    uint4 av0 = *(const uint4*)(ga + k0);
    uint4 av1 = *(const uint4*)(ga + k0 + 32);
    uint4 bv0 = *(const uint4*)(gb + k0);
    uint4 bv1 = *(const uint4*)(gb + k0 + 32);
    __syncthreads();
    *(uint4*)&As[lrow][lseg * 8] = av0;
    *(uint4*)&As[lrow][32 + lseg * 8] = av1;
    *(uint4*)&Bs[lrow][lseg * 8] = bv0;
    *(uint4*)&Bs[lrow][32 + lseg * 8] = bv1;
    __syncthreads();
    #pragma unroll
    for (int ks = 0; ks < 2; ++ks) {
      short8 af[2], bf[2];
      #pragma unroll
      for (int mt = 0; mt < 2; ++mt) af[mt] = *(const short8*)&As[wm * 32 + mt * 16 + c16][ks * 32 + quad * 8];
      #pragma unroll
      for (int nt = 0; nt < 2; ++nt) bf[nt] = *(const short8*)&Bs[wn * 32 + nt * 16 + c16][ks * 32 + quad * 8];
      #pragma unroll
      for (int mt = 0; mt < 2; ++mt)
        #pragma unroll
        for (int nt = 0; nt < 2; ++nt)
          acc[mt][nt] = MFMA16(af[mt], bf[nt], acc[mt][nt]);
    }
  }
  #pragma unroll
  for (int mt = 0; mt < 2; ++mt) {
    #pragma unroll
    for (int nt = 0; nt < 2; ++nt) {
      int rg0 = m0 + wm * 32 + mt * 16 + quad * 4;
      int cg = n0 + wn * 32 + nt * 16 + c16;
      #pragma unroll
      for (int r = 0; r < 4; ++r) {
        float v = acc[mt][nt][r];
        int m = rg0 + r;
        if (EPI == 0) {
          int s = cg / 384, rem = cg % 384, hh = rem / 64, d = rem % 64;
          int b = m / NT, nn = m % NT;
          u16 bv = f2bf(v);
          size_t bh = (size_t)(b * NH + hh);
          if (s == 0)      qout[(bh * NT + nn) * 64 + d] = bv;
          else if (s == 1) kout[(bh * NT + nn) * 64 + d] = bv;
          else             vtout[(bh * 64 + d) * NT + nn] = bv;
        } else if (EPI == 1 || EPI == 3) {
          atomicAdd(&outf[(size_t)m * CD + cg], v);
        } else {
          v += bias[cg];
          v = 0.5f * v * (1.0f + erff(v * 0.70710678118f));
          outb[(size_t)m * HID + cg] = f2bf(v);
        }
      }
    }
  }
}

// ---------------- attention pass 1: partial (m, l) per column chunk ----------------
// grid (NT/64, BB*NH, CS), block 256 (4 waves x 16 q-rows)
__global__ __launch_bounds__(256) void attn_pass1(
    const u16* __restrict__ qb, const u16* __restrict__ kb, float* __restrict__ ml) {
  int bh = blockIdx.y, chunk = blockIdx.z;
  int q0 = blockIdx.x * 64;
  int t = threadIdx.x, w = t >> 6, lane = t & 63, quad = lane >> 4, c16 = lane & 15;

  const u16* qp = qb + ((size_t)bh * NT + q0 + w * 16 + c16) * HD;
  short8 qf0 = *(const short8*)(qp + quad * 8);
  short8 qf1 = *(const short8*)(qp + 32 + quad * 8);
  const u16* kbase = kb + (size_t)bh * NT * HD;

  float m_i[4], l_i[4];
  #pragma unroll
  for (int r = 0; r < 4; ++r) { m_i[r] = -1e30f; l_i[r] = 0.f; }

  for (int ct = 0; ct < CTILES; ++ct) {
    int col0 = (chunk * CTILES + ct) * 64;
    floatx4 s_acc[4] = {};
    #pragma unroll
    for (int nt = 0; nt < 4; ++nt) {
      const u16* kp = kbase + (size_t)(col0 + nt * 16 + c16) * HD + quad * 8;
      s_acc[nt] = MFMA16(qf0, *(const short8*)(kp), s_acc[nt]);
      s_acc[nt] = MFMA16(qf1, *(const short8*)(kp + 32), s_acc[nt]);
    }
    #pragma unroll
    for (int r = 0; r < 4; ++r) {
      float rm = fmaxf(fmaxf(s_acc[0][r], s_acc[1][r]), fmaxf(s_acc[2][r], s_acc[3][r])) * SCALE;
      #pragma unroll
      for (int off = 1; off < 16; off <<= 1) rm = fmaxf(rm, __shfl_xor(rm, off));
      float nm = fmaxf(m_i[r], rm);
      float ps = 0.f;
      #pragma unroll
      for (int nt = 0; nt < 4; ++nt) ps += __expf(s_acc[nt][r] * SCALE - nm);
      #pragma unroll
      for (int off = 1; off < 16; off <<= 1) ps += __shfl_xor(ps, off);
      l_i[r] = l_i[r] * __expf(m_i[r] - nm) + ps;
      m_i[r] = nm;
    }
  }
  if (c16 == 0) {
    #pragma unroll
    for (int r = 0; r < 4; ++r) {
      int row = q0 + w * 16 + quad * 4 + r;
      float* p = ml + ((size_t)(bh * NT + row) * CS + chunk) * 2;
      p[0] = m_i[r]; p[1] = l_i[r];
    }
  }
}

// ---------------- attention pass 2: write attn, partial O per chunk ----------------
__global__ __launch_bounds__(256) void attn_pass2(
    const u16* __restrict__ qb, const u16* __restrict__ kb, const u16* __restrict__ vtb,
    const float* __restrict__ ml, float* __restrict__ attn_out, float* __restrict__ o_part) {
  __shared__ __align__(16) u16 Plds[4][16][72];
  __shared__ float mfin[64], rlfin[64];
  int bh = blockIdx.y, chunk = blockIdx.z;
  int b = bh / NH, hh = bh % NH;
  int q0 = blockIdx.x * 64;
  int t = threadIdx.x, w = t >> 6, lane = t & 63, quad = lane >> 4, c16 = lane & 15;

  if (t < 64) {
    const float* p = ml + (size_t)(bh * NT + q0 + t) * CS * 2;
    float mm = -1e30f;
    #pragma unroll
    for (int c = 0; c < CS; ++c) mm = fmaxf(mm, p[c * 2]);
    float ll = 0.f;
    #pragma unroll
    for (int c = 0; c < CS; ++c) ll += p[c * 2 + 1] * __expf(p[c * 2] - mm);
    mfin[t] = mm; rlfin[t] = 1.0f / ll;
  }
  __syncthreads();
  float m_i[4], rl[4];
  #pragma unroll
  for (int r = 0; r < 4; ++r) {
    int rr = w * 16 + quad * 4 + r;
    m_i[r] = mfin[rr]; rl[r] = rlfin[rr];
  }

  const u16* qp = qb + ((size_t)bh * NT + q0 + w * 16 + c16) * HD;
  short8 qf0 = *(const short8*)(qp + quad * 8);
  short8 qf1 = *(const short8*)(qp + 32 + quad * 8);
  const u16* kbase = kb + (size_t)bh * NT * HD;
  const u16* vbase = vtb + (size_t)bh * HD * NT;

  floatx4 o_acc[4] = {};
  float* attn_bh = attn_out + (size_t)bh * NT * NT;
  for (int ct = 0; ct < CTILES; ++ct) {
    int col0 = (chunk * CTILES + ct) * 64;
    floatx4 s_acc[4] = {};
    #pragma unroll
    for (int nt = 0; nt < 4; ++nt) {
      const u16* kp = kbase + (size_t)(col0 + nt * 16 + c16) * HD + quad * 8;
      s_acc[nt] = MFMA16(qf0, *(const short8*)(kp), s_acc[nt]);
      s_acc[nt] = MFMA16(qf1, *(const short8*)(kp + 32), s_acc[nt]);
    }
    #pragma unroll
    for (int nt = 0; nt < 4; ++nt) {
      #pragma unroll
      for (int r = 0; r < 4; ++r) {
        float p = __expf(s_acc[nt][r] * SCALE - m_i[r]) * rl[r];
        attn_bh[(size_t)(q0 + w * 16 + quad * 4 + r) * NT + col0 + nt * 16 + c16] = p;
        Plds[w][quad * 4 + r][nt * 16 + c16] = f2bf(p);
      }
    }
    // Plds slice is per-wave private: no __syncthreads needed, compiler orders ds ops
    #pragma unroll
    for (int ks = 0; ks < 2; ++ks) {
      short8 pa = *(const short8*)&Plds[w][c16][ks * 32 + quad * 8];
      #pragma unroll
      for (int dt = 0; dt < 4; ++dt) {
        short8 vb = *(const short8*)(vbase + (size_t)(dt * 16 + c16) * NT + col0 + ks * 32 + quad * 8);
        o_acc[dt] = MFMA16(pa, vb, o_acc[dt]);
      }
    }
  }
  #pragma unroll
  for (int dt = 0; dt < 4; ++dt) {
    #pragma unroll
    for (int r = 0; r < 4; ++r) {
      int m = b * NT + q0 + w * 16 + quad * 4 + r;
      int cc = hh * 64 + dt * 16 + c16;
      o_part[((size_t)chunk * M + m) * CD + cc] = o_acc[dt][r];
    }
  }
}

// ---------------- sum partial O across chunks -> bf16 ----------------
__global__ void osum_kernel(const float* __restrict__ o_part, u16* __restrict__ o_bf) {
  int i = (blockIdx.x * 256 + threadIdx.x) * 4;
  float4 s = *(const float4*)(o_part + i);
  #pragma unroll
  for (int c = 1; c < CS; ++c) {
    float4 v = *(const float4*)(o_part + (size_t)c * M * CD + i);
    s.x += v.x; s.y += v.y; s.z += v.z; s.w += v.w;
  }
  ushort4 o; o.x = f2bf(s.x); o.y = f2bf(s.y); o.z = f2bf(s.z); o.w = f2bf(s.w);
  *(ushort4*)(o_bf + i) = o;
}

// ---------------- launch ----------------
extern "C" void kernel_launch(void* const* d_in, const int* in_sizes, int n_in,
                              void* d_out, int out_size, void* d_ws, size_t ws_size,
                              hipStream_t stream) {
  const float* x      = (const float*)d_in[0];
  const float* pos    = (const float*)d_in[1];
  const float* ln1_g  = (const float*)d_in[2];
  const float* ln1_b  = (const float*)d_in[3];
  const float* w_qkv  = (const float*)d_in[4];
  const float* w_proj = (const float*)d_in[5];
  const float* b_proj = (const float*)d_in[6];
  const float* ln2_g  = (const float*)d_in[7];
  const float* ln2_b  = (const float*)d_in[8];
  const float* w_fc1  = (const float*)d_in[9];
  const float* b_fc1  = (const float*)d_in[10];
  const float* w_fc2  = (const float*)d_in[11];
  const float* b_fc2  = (const float*)d_in[12];

  float* out      = (float*)d_out;
  float* attn_out = out + (size_t)M * CD;

  char* ws = (char*)d_ws;
  size_t o = 0;
  auto carve = [&](size_t bytes) { char* p = ws + o; o += bytes; return p; };
  float* x1    = (float*)carve((size_t)M * CD * 4);
  u16* h1      = (u16*)carve((size_t)M * CD * 2);
  u16* wqkv_b  = (u16*)carve((size_t)3 * CD * CD * 2);
  u16* wproj_b = (u16*)carve((size_t)CD * CD * 2);
  u16* wfc1_b  = (u16*)carve((size_t)HID * CD * 2);
  u16* wfc2_b  = (u16*)carve((size_t)CD * HID * 2);
  u16* q_bf    = (u16*)carve((size_t)BB * NH * NT * HD * 2);
  u16* k_bf    = (u16*)carve((size_t)BB * NH * NT * HD * 2);
  u16* vt_bf   = (u16*)carve((size_t)BB * NH * NT * HD * 2);
  u16* o_bf    = (u16*)carve((size_t)M * CD * 2);
  float* x2    = (float*)carve((size_t)M * CD * 4);
  u16* h2      = (u16*)carve((size_t)M * CD * 2);
  u16* g_bf    = (u16*)carve((size_t)M * HID * 2);
  float* ml    = (float*)carve((size_t)NH * BB * NT * CS * 2 * 4);
  float* o_part= (float*)carve((size_t)CS * M * CD * 4);
  (void)ws_size; (void)in_sizes; (void)n_in; (void)out_size;

  // weight converts
  cvt_bf16<<<(3 * CD * CD) / 1024, 256, 0, stream>>>(w_qkv, wqkv_b, 3 * CD * CD);
  cvt_bf16<<<(CD * CD) / 1024, 256, 0, stream>>>(w_proj, wproj_b, CD * CD);
  cvt_bf16<<<(HID * CD) / 1024, 256, 0, stream>>>(w_fc1, wfc1_b, HID * CD);
  cvt_bf16<<<(CD * HID) / 1024, 256, 0, stream>>>(w_fc2, wfc2_b, CD * HID);

  // x1 = x + pos; h1 = LN1(x1)
  ln_kernel<<<M, 128, 0, stream>>>(x, pos, ln1_g, ln1_b, x1, h1);

  // qkv = h1 @ w_qkv^T, scatter to q/k/vT
  gemm_bt<0, 1><<<dim3((3 * CD) / 64, M / 64), 256, 0, stream>>>(
      h1, wqkv_b, CD, nullptr, nullptr, nullptr, q_bf, k_bf, vt_bf);

  // attention (column-chunked two-pass)
  attn_pass1<<<dim3(NT / 64, BB * NH, CS), 256, 0, stream>>>(q_bf, k_bf, ml);
  attn_pass2<<<dim3(NT / 64, BB * NH, CS), 256, 0, stream>>>(q_bf, k_bf, vt_bf, ml, attn_out, o_part);
  osum_kernel<<<(M * CD) / 1024, 256, 0, stream>>>(o_part, o_bf);

  // x2 = x1 + b_proj + o @ w_proj^T  (split-K atomic)
  init_add<<<(M * CD) / 1024, 256, 0, stream>>>(x1, b_proj, x2);
  gemm_bt<1, 2><<<dim3(CD / 64, M / 64, 2), 256, 0, stream>>>(
      o_bf, wproj_b, CD, nullptr, x2, nullptr, nullptr, nullptr, nullptr);

  // h2 = LN2(x2)
  ln_kernel<<<M, 128, 0, stream>>>(x2, nullptr, ln2_g, ln2_b, nullptr, h2);

  // g = gelu(h2 @ w_fc1^T + b_fc1)
  gemm_bt<2, 1><<<dim3(HID / 64, M / 64), 256, 0, stream>>>(
      h2, wfc1_b, CD, b_fc1, nullptr, g_bf, nullptr, nullptr, nullptr);

  // out = x2 + b_fc2 + g @ w_fc2^T  (split-K atomic)
  init_add<<<(M * CD) / 1024, 256, 0, stream>>>(x2, b_fc2, out);
  gemm_bt<3, 4><<<dim3(CD / 64, M / 64, 4), 256, 0, stream>>>(
      g_bf, wfc2_b, HID, b_fc2, out, nullptr, nullptr, nullptr, nullptr);
}

// Round 3
// 533.526 us; speedup vs baseline: 1.0423x; 1.0423x over previous
//
#include <hip/hip_runtime.h>
#include <math.h>

typedef unsigned short u16;
typedef unsigned int   u32;
typedef __attribute__((ext_vector_type(8))) short short8;
typedef __attribute__((ext_vector_type(4))) float floatx4;

#define MFMA16(a,b,c) __builtin_amdgcn_mfma_f32_16x16x32_bf16((a),(b),(c),0,0,0)

constexpr int BB  = 2;
constexpr int NT  = 2240;
constexpr int CD  = 384;
constexpr int NH  = 6;
constexpr int HD  = 64;
constexpr int HID = 1536;
constexpr int M   = BB * NT;          // 4480
constexpr int CS  = 5;                // attn column chunks
constexpr int CTILES = NT / 64 / CS;  // 7 col-tiles per chunk
constexpr float SCALE = 0.125f;

__device__ inline u16 f2bf(float f) {
  u32 u = __float_as_uint(f);
  u = (u + 0x7fffu + ((u >> 16) & 1u)) >> 16;
  return (u16)u;
}
__device__ inline float bf2f(u16 b) { return __uint_as_float(((u32)b) << 16); }

// ---------------- weight fp32 -> bf16 convert ----------------
__global__ void cvt_bf16(const float* __restrict__ src, u16* __restrict__ dst, int n) {
  int i = (blockIdx.x * 256 + threadIdx.x) * 4;
  if (i < n) {
    float4 v = *(const float4*)(src + i);
    ushort4 o; o.x = f2bf(v.x); o.y = f2bf(v.y); o.z = f2bf(v.z); o.w = f2bf(v.w);
    *(ushort4*)(dst + i) = o;
  }
}

// ---------------- layernorm (+optional pos add, +optional x save) ----------------
__global__ __launch_bounds__(128) void ln_kernel(
    const float* __restrict__ xin, const float* __restrict__ pos,
    const float* __restrict__ g, const float* __restrict__ bta,
    float* __restrict__ x1out, u16* __restrict__ hout) {
  int row = blockIdx.x;
  int n = row % NT;
  int t = threadIdx.x;
  const float* xr = xin + (size_t)row * CD;
  float v[3], s1 = 0.f, s2 = 0.f;
  #pragma unroll
  for (int j = 0; j < 3; ++j) {
    int c = t + j * 128;
    float x = xr[c];
    if (pos) x += pos[(size_t)n * CD + c];
    v[j] = x; s1 += x; s2 += x * x;
  }
  #pragma unroll
  for (int off = 32; off; off >>= 1) { s1 += __shfl_down(s1, off); s2 += __shfl_down(s2, off); }
  __shared__ float rbuf[4];
  __shared__ float stats[2];
  int lane = t & 63, wid = t >> 6;
  if (lane == 0) { rbuf[wid] = s1; rbuf[2 + wid] = s2; }
  __syncthreads();
  if (t == 0) {
    float a = rbuf[0] + rbuf[1], b2 = rbuf[2] + rbuf[3];
    float mu = a / CD;
    float var = b2 / CD - mu * mu;
    stats[0] = mu; stats[1] = rsqrtf(var + 1e-5f);
  }
  __syncthreads();
  float mu = stats[0], rs = stats[1];
  #pragma unroll
  for (int j = 0; j < 3; ++j) {
    int c = t + j * 128;
    float h = (v[j] - mu) * rs * g[c] + bta[c];
    hout[(size_t)row * CD + c] = f2bf(h);
    if (x1out) x1out[(size_t)row * CD + c] = v[j];
  }
}

// ---------------- fused: x2 = x1 + bias + pp0 + pp1 ; h2 = LN2(x2) ----------------
__global__ __launch_bounds__(128) void red_ln_kernel(
    const float* __restrict__ pp, const float* __restrict__ x1,
    const float* __restrict__ bias,
    const float* __restrict__ g, const float* __restrict__ bta,
    float* __restrict__ x2out, u16* __restrict__ hout) {
  int row = blockIdx.x;
  int t = threadIdx.x;
  float v[3], s1 = 0.f, s2 = 0.f;
  #pragma unroll
  for (int j = 0; j < 3; ++j) {
    int c = t + j * 128;
    size_t idx = (size_t)row * CD + c;
    float x = x1[idx] + bias[c] + pp[idx] + pp[(size_t)M * CD + idx];
    v[j] = x; s1 += x; s2 += x * x;
  }
  #pragma unroll
  for (int off = 32; off; off >>= 1) { s1 += __shfl_down(s1, off); s2 += __shfl_down(s2, off); }
  __shared__ float rbuf[4];
  __shared__ float stats[2];
  int lane = t & 63, wid = t >> 6;
  if (lane == 0) { rbuf[wid] = s1; rbuf[2 + wid] = s2; }
  __syncthreads();
  if (t == 0) {
    float a = rbuf[0] + rbuf[1], b2 = rbuf[2] + rbuf[3];
    float mu = a / CD;
    float var = b2 / CD - mu * mu;
    stats[0] = mu; stats[1] = rsqrtf(var + 1e-5f);
  }
  __syncthreads();
  float mu = stats[0], rs = stats[1];
  #pragma unroll
  for (int j = 0; j < 3; ++j) {
    int c = t + j * 128;
    size_t idx = (size_t)row * CD + c;
    x2out[idx] = v[j];
    hout[idx] = f2bf((v[j] - mu) * rs * g[c] + bta[c]);
  }
}

// ---------------- out = x2 + bias + pf0+pf1+pf2+pf3 ----------------
__global__ void fc2_reduce(const float* __restrict__ pf, const float* __restrict__ x2,
                           const float* __restrict__ bias, float* __restrict__ outf) {
  int i = (blockIdx.x * 256 + threadIdx.x) * 4;
  float4 s = *(const float4*)(x2 + i);
  float4 b = *(const float4*)(bias + (i % CD));
  s.x += b.x; s.y += b.y; s.z += b.z; s.w += b.w;
  #pragma unroll
  for (int c = 0; c < 4; ++c) {
    float4 v = *(const float4*)(pf + (size_t)c * M * CD + i);
    s.x += v.x; s.y += v.y; s.z += v.z; s.w += v.w;
  }
  *(float4*)(outf + i) = s;
}

// ---------------- bf16 GEMM: out[M,N] = A[M,K] @ W[N,K]^T ----------------
// EPI: 0=qkv scatter, 1=fp32 partial store (per-z buffer), 2=fc1(bias+gelu->bf16)
template <int EPI, int SPLITK>
__global__ __launch_bounds__(256) void gemm_bt(
    const u16* __restrict__ A, const u16* __restrict__ Wt, int K,
    const float* __restrict__ bias,
    float* __restrict__ outf, u16* __restrict__ outb,
    u16* __restrict__ qout, u16* __restrict__ kout, u16* __restrict__ vtout) {
  __shared__ __align__(16) u16 As[64][72];
  __shared__ __align__(16) u16 Bs[64][72];
  int m0 = blockIdx.y * 64, n0 = blockIdx.x * 64;
  int Ksub = K / SPLITK;
  int koff = blockIdx.z * Ksub;
  int t = threadIdx.x;
  int lane = t & 63, w = t >> 6, wm = w & 1, wn = w >> 1;
  int quad = lane >> 4, c16 = lane & 15;
  int lrow = t >> 2, lseg = t & 3;
  const u16* ga = A + (size_t)(m0 + lrow) * K + koff + lseg * 8;
  const u16* gb = Wt + (size_t)(n0 + lrow) * K + koff + lseg * 8;
  floatx4 acc[2][2] = {};
  for (int k0 = 0; k0 < Ksub; k0 += 64) {
    uint4 av0 = *(const uint4*)(ga + k0);
    uint4 av1 = *(const uint4*)(ga + k0 + 32);
    uint4 bv0 = *(const uint4*)(gb + k0);
    uint4 bv1 = *(const uint4*)(gb + k0 + 32);
    __syncthreads();
    *(uint4*)&As[lrow][lseg * 8] = av0;
    *(uint4*)&As[lrow][32 + lseg * 8] = av1;
    *(uint4*)&Bs[lrow][lseg * 8] = bv0;
    *(uint4*)&Bs[lrow][32 + lseg * 8] = bv1;
    __syncthreads();
    #pragma unroll
    for (int ks = 0; ks < 2; ++ks) {
      short8 af[2], bf[2];
      #pragma unroll
      for (int mt = 0; mt < 2; ++mt) af[mt] = *(const short8*)&As[wm * 32 + mt * 16 + c16][ks * 32 + quad * 8];
      #pragma unroll
      for (int nt = 0; nt < 2; ++nt) bf[nt] = *(const short8*)&Bs[wn * 32 + nt * 16 + c16][ks * 32 + quad * 8];
      #pragma unroll
      for (int mt = 0; mt < 2; ++mt)
        #pragma unroll
        for (int nt = 0; nt < 2; ++nt)
          acc[mt][nt] = MFMA16(af[mt], bf[nt], acc[mt][nt]);
    }
  }
  float* outz = (EPI == 1) ? outf + (size_t)blockIdx.z * M * CD : outf;
  #pragma unroll
  for (int mt = 0; mt < 2; ++mt) {
    #pragma unroll
    for (int nt = 0; nt < 2; ++nt) {
      int rg0 = m0 + wm * 32 + mt * 16 + quad * 4;
      int cg = n0 + wn * 32 + nt * 16 + c16;
      #pragma unroll
      for (int r = 0; r < 4; ++r) {
        float v = acc[mt][nt][r];
        int m = rg0 + r;
        if (EPI == 0) {
          int s = cg / 384, rem = cg % 384, hh = rem / 64, d = rem % 64;
          int b = m / NT, nn = m % NT;
          u16 bv = f2bf(v);
          size_t bh = (size_t)(b * NH + hh);
          if (s == 0)      qout[(bh * NT + nn) * 64 + d] = bv;
          else if (s == 1) kout[(bh * NT + nn) * 64 + d] = bv;
          else             vtout[(bh * 64 + d) * NT + nn] = bv;
        } else if (EPI == 1) {
          outz[(size_t)m * CD + cg] = v;
        } else {
          v += bias[cg];
          v = 0.5f * v * (1.0f + erff(v * 0.70710678118f));
          outb[(size_t)m * HID + cg] = f2bf(v);
        }
      }
    }
  }
}

// ---------------- attention pass 1: partial (m, l) per column chunk ----------------
__global__ __launch_bounds__(256) void attn_pass1(
    const u16* __restrict__ qb, const u16* __restrict__ kb, float* __restrict__ ml) {
  int bh = blockIdx.y, chunk = blockIdx.z;
  int q0 = blockIdx.x * 64;
  int t = threadIdx.x, w = t >> 6, lane = t & 63, quad = lane >> 4, c16 = lane & 15;

  const u16* qp = qb + ((size_t)bh * NT + q0 + w * 16 + c16) * HD;
  short8 qf0 = *(const short8*)(qp + quad * 8);
  short8 qf1 = *(const short8*)(qp + 32 + quad * 8);
  const u16* kbase = kb + (size_t)bh * NT * HD;

  float m_i[4], l_i[4];
  #pragma unroll
  for (int r = 0; r < 4; ++r) { m_i[r] = -1e30f; l_i[r] = 0.f; }

  for (int ct = 0; ct < CTILES; ++ct) {
    int col0 = (chunk * CTILES + ct) * 64;
    floatx4 s_acc[4] = {};
    #pragma unroll
    for (int nt = 0; nt < 4; ++nt) {
      const u16* kp = kbase + (size_t)(col0 + nt * 16 + c16) * HD + quad * 8;
      s_acc[nt] = MFMA16(qf0, *(const short8*)(kp), s_acc[nt]);
      s_acc[nt] = MFMA16(qf1, *(const short8*)(kp + 32), s_acc[nt]);
    }
    #pragma unroll
    for (int r = 0; r < 4; ++r) {
      float rm = fmaxf(fmaxf(s_acc[0][r], s_acc[1][r]), fmaxf(s_acc[2][r], s_acc[3][r])) * SCALE;
      #pragma unroll
      for (int off = 1; off < 16; off <<= 1) rm = fmaxf(rm, __shfl_xor(rm, off));
      float nm = fmaxf(m_i[r], rm);
      float ps = 0.f;
      #pragma unroll
      for (int nt = 0; nt < 4; ++nt) ps += __expf(s_acc[nt][r] * SCALE - nm);
      #pragma unroll
      for (int off = 1; off < 16; off <<= 1) ps += __shfl_xor(ps, off);
      l_i[r] = l_i[r] * __expf(m_i[r] - nm) + ps;
      m_i[r] = nm;
    }
  }
  if (c16 == 0) {
    #pragma unroll
    for (int r = 0; r < 4; ++r) {
      int row = q0 + w * 16 + quad * 4 + r;
      float* p = ml + ((size_t)(bh * NT + row) * CS + chunk) * 2;
      p[0] = m_i[r]; p[1] = l_i[r];
    }
  }
}

// ---------------- attention pass 2: write attn, bf16 partial O per chunk ----------------
__global__ __launch_bounds__(256) void attn_pass2(
    const u16* __restrict__ qb, const u16* __restrict__ kb, const u16* __restrict__ vtb,
    const float* __restrict__ ml, float* __restrict__ attn_out, u16* __restrict__ o_part) {
  __shared__ __align__(16) u16 Plds[4][16][72];
  __shared__ float mfin[64], rlfin[64];
  int bh = blockIdx.y, chunk = blockIdx.z;
  int b = bh / NH, hh = bh % NH;
  int q0 = blockIdx.x * 64;
  int t = threadIdx.x, w = t >> 6, lane = t & 63, quad = lane >> 4, c16 = lane & 15;

  if (t < 64) {
    const float* p = ml + (size_t)(bh * NT + q0 + t) * CS * 2;
    float mm = -1e30f;
    #pragma unroll
    for (int c = 0; c < CS; ++c) mm = fmaxf(mm, p[c * 2]);
    float ll = 0.f;
    #pragma unroll
    for (int c = 0; c < CS; ++c) ll += p[c * 2 + 1] * __expf(p[c * 2] - mm);
    mfin[t] = mm; rlfin[t] = 1.0f / ll;
  }
  __syncthreads();
  float m_i[4], rl[4];
  #pragma unroll
  for (int r = 0; r < 4; ++r) {
    int rr = w * 16 + quad * 4 + r;
    m_i[r] = mfin[rr]; rl[r] = rlfin[rr];
  }

  const u16* qp = qb + ((size_t)bh * NT + q0 + w * 16 + c16) * HD;
  short8 qf0 = *(const short8*)(qp + quad * 8);
  short8 qf1 = *(const short8*)(qp + 32 + quad * 8);
  const u16* kbase = kb + (size_t)bh * NT * HD;
  const u16* vbase = vtb + (size_t)bh * HD * NT;

  floatx4 o_acc[4] = {};
  float* attn_bh = attn_out + (size_t)bh * NT * NT;
  for (int ct = 0; ct < CTILES; ++ct) {
    int col0 = (chunk * CTILES + ct) * 64;
    floatx4 s_acc[4] = {};
    #pragma unroll
    for (int nt = 0; nt < 4; ++nt) {
      const u16* kp = kbase + (size_t)(col0 + nt * 16 + c16) * HD + quad * 8;
      s_acc[nt] = MFMA16(qf0, *(const short8*)(kp), s_acc[nt]);
      s_acc[nt] = MFMA16(qf1, *(const short8*)(kp + 32), s_acc[nt]);
    }
    #pragma unroll
    for (int nt = 0; nt < 4; ++nt) {
      #pragma unroll
      for (int r = 0; r < 4; ++r) {
        float p = __expf(s_acc[nt][r] * SCALE - m_i[r]) * rl[r];
        attn_bh[(size_t)(q0 + w * 16 + quad * 4 + r) * NT + col0 + nt * 16 + c16] = p;
        Plds[w][quad * 4 + r][nt * 16 + c16] = f2bf(p);
      }
    }
    #pragma unroll
    for (int ks = 0; ks < 2; ++ks) {
      short8 pa = *(const short8*)&Plds[w][c16][ks * 32 + quad * 8];
      #pragma unroll
      for (int dt = 0; dt < 4; ++dt) {
        short8 vb = *(const short8*)(vbase + (size_t)(dt * 16 + c16) * NT + col0 + ks * 32 + quad * 8);
        o_acc[dt] = MFMA16(pa, vb, o_acc[dt]);
      }
    }
  }
  #pragma unroll
  for (int dt = 0; dt < 4; ++dt) {
    #pragma unroll
    for (int r = 0; r < 4; ++r) {
      int m = b * NT + q0 + w * 16 + quad * 4 + r;
      int cc = hh * 64 + dt * 16 + c16;
      o_part[((size_t)chunk * M + m) * CD + cc] = f2bf(o_acc[dt][r]);
    }
  }
}

// ---------------- sum bf16 partial O across chunks -> bf16 ----------------
__global__ void osum_kernel(const u16* __restrict__ o_part, u16* __restrict__ o_bf) {
  int i = (blockIdx.x * 256 + threadIdx.x) * 4;
  float4 s = {0.f, 0.f, 0.f, 0.f};
  #pragma unroll
  for (int c = 0; c < CS; ++c) {
    ushort4 v = *(const ushort4*)(o_part + (size_t)c * M * CD + i);
    s.x += bf2f(v.x); s.y += bf2f(v.y); s.z += bf2f(v.z); s.w += bf2f(v.w);
  }
  ushort4 o; o.x = f2bf(s.x); o.y = f2bf(s.y); o.z = f2bf(s.z); o.w = f2bf(s.w);
  *(ushort4*)(o_bf + i) = o;
}

// ---------------- launch ----------------
extern "C" void kernel_launch(void* const* d_in, const int* in_sizes, int n_in,
                              void* d_out, int out_size, void* d_ws, size_t ws_size,
                              hipStream_t stream) {
  const float* x      = (const float*)d_in[0];
  const float* pos    = (const float*)d_in[1];
  const float* ln1_g  = (const float*)d_in[2];
  const float* ln1_b  = (const float*)d_in[3];
  const float* w_qkv  = (const float*)d_in[4];
  const float* w_proj = (const float*)d_in[5];
  const float* b_proj = (const float*)d_in[6];
  const float* ln2_g  = (const float*)d_in[7];
  const float* ln2_b  = (const float*)d_in[8];
  const float* w_fc1  = (const float*)d_in[9];
  const float* b_fc1  = (const float*)d_in[10];
  const float* w_fc2  = (const float*)d_in[11];
  const float* b_fc2  = (const float*)d_in[12];

  float* out      = (float*)d_out;
  float* attn_out = out + (size_t)M * CD;

  char* ws = (char*)d_ws;
  size_t o = 0;
  auto carve = [&](size_t bytes) { char* p = ws + o; o += bytes; return p; };
  float* x1    = (float*)carve((size_t)M * CD * 4);
  u16* h1      = (u16*)carve((size_t)M * CD * 2);
  u16* wqkv_b  = (u16*)carve((size_t)3 * CD * CD * 2);
  u16* wproj_b = (u16*)carve((size_t)CD * CD * 2);
  u16* wfc1_b  = (u16*)carve((size_t)HID * CD * 2);
  u16* wfc2_b  = (u16*)carve((size_t)CD * HID * 2);
  u16* q_bf    = (u16*)carve((size_t)BB * NH * NT * HD * 2);
  u16* k_bf    = (u16*)carve((size_t)BB * NH * NT * HD * 2);
  u16* vt_bf   = (u16*)carve((size_t)BB * NH * NT * HD * 2);
  u16* o_bf    = (u16*)carve((size_t)M * CD * 2);
  float* x2    = (float*)carve((size_t)M * CD * 4);
  u16* h2      = (u16*)carve((size_t)M * CD * 2);
  u16* g_bf    = (u16*)carve((size_t)M * HID * 2);
  float* ml    = (float*)carve((size_t)NH * BB * NT * CS * 2 * 4);
  u16* o_part  = (u16*)carve((size_t)CS * M * CD * 2);
  float* pp    = (float*)carve((size_t)2 * M * CD * 4);
  float* pf    = (float*)carve((size_t)4 * M * CD * 4);
  (void)ws_size; (void)in_sizes; (void)n_in; (void)out_size;

  // weight converts
  cvt_bf16<<<(3 * CD * CD) / 1024, 256, 0, stream>>>(w_qkv, wqkv_b, 3 * CD * CD);
  cvt_bf16<<<(CD * CD) / 1024, 256, 0, stream>>>(w_proj, wproj_b, CD * CD);
  cvt_bf16<<<(HID * CD) / 1024, 256, 0, stream>>>(w_fc1, wfc1_b, HID * CD);
  cvt_bf16<<<(CD * HID) / 1024, 256, 0, stream>>>(w_fc2, wfc2_b, CD * HID);

  // x1 = x + pos; h1 = LN1(x1)
  ln_kernel<<<M, 128, 0, stream>>>(x, pos, ln1_g, ln1_b, x1, h1);

  // qkv = h1 @ w_qkv^T, scatter to q/k/vT
  gemm_bt<0, 1><<<dim3((3 * CD) / 64, M / 64), 256, 0, stream>>>(
      h1, wqkv_b, CD, nullptr, nullptr, nullptr, q_bf, k_bf, vt_bf);

  // attention (column-chunked two-pass)
  attn_pass1<<<dim3(NT / 64, BB * NH, CS), 256, 0, stream>>>(q_bf, k_bf, ml);
  attn_pass2<<<dim3(NT / 64, BB * NH, CS), 256, 0, stream>>>(q_bf, k_bf, vt_bf, ml, attn_out, o_part);
  osum_kernel<<<(M * CD) / 1024, 256, 0, stream>>>(o_part, o_bf);

  // proj partials (deterministic split-K=2), then fused reduce + LN2
  gemm_bt<1, 2><<<dim3(CD / 64, M / 64, 2), 256, 0, stream>>>(
      o_bf, wproj_b, CD, nullptr, pp, nullptr, nullptr, nullptr, nullptr);
  red_ln_kernel<<<M, 128, 0, stream>>>(pp, x1, b_proj, ln2_g, ln2_b, x2, h2);

  // g = gelu(h2 @ w_fc1^T + b_fc1)
  gemm_bt<2, 1><<<dim3(HID / 64, M / 64), 256, 0, stream>>>(
      h2, wfc1_b, CD, b_fc1, nullptr, g_bf, nullptr, nullptr, nullptr);

  // fc2 partials (deterministic split-K=4), then reduce
  gemm_bt<1, 4><<<dim3(CD / 64, M / 64, 4), 256, 0, stream>>>(
      g_bf, wfc2_b, HID, nullptr, pf, nullptr, nullptr, nullptr, nullptr);
  fc2_reduce<<<(M * CD) / 1024, 256, 0, stream>>>(pf, x2, b_fc2, out);
}